// Round 3
// baseline (229.493 us; speedup 1.0000x reference)
//
#include <hip/hip_runtime.h>

// B=16, T=256, C=6, E=512, H=8, hd=64.
// Inputs fp32; OUTPUT fp32. Compute in bf16 MFMA; biases added in fp32.
//
// Round 7: real 8-phase 256x256 GEMM (m201 template) for QKV and proj.
//  - BM=BN=256, BK=64, 512 thr = 8 waves (2M x 4N), per-wave out 128x64.
//  - LDS 128 KB: 2 dbuf x (A 256x64 + B 256x64) bf16. Even K-tiles in buf0,
//    odd in buf1. Per iteration (2 K-tiles): 8 phases, each
//    {ds_reads | 1 half-tile stage (2 gl_lds)} -> barrier -> lgkmcnt(0) ->
//    setprio(1) -> 16 MFMA -> setprio(0) -> [vmcnt(2) @ p4/p8] -> barrier.
//  - Stage stream (1 half-tile/phase, 4 slots/tile): tile v=2i+1 staged at
//    [prev p8: B-h0][p1: B-h1][p2: A-h0][p3: A-h1] (buf1);
//    tile w=2i+2 at [p4: B-h0][p5: B-h1][p6: A-h0][p7: A-h1] (buf0).
//    vmcnt(2) at p4 covers v (its newest load is 1 slot older than the 2
//    allowed in flight); vmcnt(2) at p8 covers w. Never 0 except final drain.
//  - T2 swizzle on 128-B LDS rows: 16B-granule g stored at g^(row&7);
//    applied via pre-swizzled global source (gl_lds dest stays linear) and
//    the same XOR on ds_read -> 2 lanes/bank (free).

typedef unsigned short u16;
typedef short bf16x8 __attribute__((ext_vector_type(8)));   // 8 bf16 = 4 VGPRs
typedef float f32x4 __attribute__((ext_vector_type(4)));
typedef u16 u16x4 __attribute__((ext_vector_type(4)));

#define MFMA16(a, b, c) __builtin_amdgcn_mfma_f32_16x16x32_bf16((a), (b), (c), 0, 0, 0)

__device__ __forceinline__ u16 f2b(float f) {
  union { float f; unsigned u; } v; v.f = f;
  unsigned r = v.u + 0x7fffu + ((v.u >> 16) & 1u);   // RNE (finite inputs)
  return (u16)(r >> 16);
}
__device__ __forceinline__ void gl_lds16(const void* g, void* l) {
  __builtin_amdgcn_global_load_lds(
      (const __attribute__((address_space(1))) void*)g,
      (__attribute__((address_space(3))) void*)l, 16, 0, 0);
}

// ---------------------------------------------------------------------------
// fp32 -> bf16 converters
// ---------------------------------------------------------------------------
__global__ void cvt_w(const float* W0, const float* W1, const float* W2,
                      const float* W3, u16* dst) {
  const float* src = (blockIdx.y == 0) ? W0 : (blockIdx.y == 1) ? W1
                   : (blockIdx.y == 2) ? W2 : W3;
  const int idx = (blockIdx.x * 256 + threadIdx.x) * 4;
  f32x4 v = *(const f32x4*)(src + idx);
  u16x4 o; o.x = f2b(v.x); o.y = f2b(v.y); o.z = f2b(v.z); o.w = f2b(v.w);
  *(u16x4*)(dst + (size_t)blockIdx.y * 262144 + idx) = o;
}

__global__ void cvt_x(const float* __restrict__ src, u16* __restrict__ dst) {
  const size_t idx = ((size_t)blockIdx.x * 256 + threadIdx.x) * 4;
  f32x4 v = *(const f32x4*)(src + idx);
  u16x4 o; o.x = f2b(v.x); o.y = f2b(v.y); o.z = f2b(v.z); o.w = f2b(v.w);
  *(u16x4*)(dst + idx) = o;
}

// ---------------------------------------------------------------------------
// 8-phase 256x256 BT-GEMM.  C[m][n] = sum_k A[m][k]*Wf[n][k] + bias[n].
// grid.x = m-block (m0 = x*256), grid.y = n-block over the FUSED n-space
// (qkv: Wf = [Wq;Wk;Wv] 1536x512, grid.y=6, sel=by>>1 picks output/bias;
//  proj: Wf = Wp 512x512, grid.y=2, sel=0).
// qkv_mode=1: bf16 scatter-store to [b,h,c,t,d].  qkv_mode=0: fp32 row-major.
// ---------------------------------------------------------------------------
#define BARX() __builtin_amdgcn_s_barrier()
#define WLGK() asm volatile("s_waitcnt lgkmcnt(0)" ::: "memory")
#define VMW(n) asm volatile("s_waitcnt vmcnt(" #n ")" ::: "memory")

#define STG_A(buf, half, t) do { \
  gl_lds16(aS0 + (size_t)(half) * 131072 + (t) * 128,         ldsA##buf + (half) * 16384 + fo0); \
  gl_lds16(aS0 + (size_t)(half) * 131072 + 65536 + (t) * 128, ldsA##buf + (half) * 16384 + fo1); \
} while (0)
#define STG_B(buf, half, t) do { \
  gl_lds16(bS0 + (size_t)(half) * 131072 + (t) * 128,         ldsB##buf + (half) * 16384 + fo0); \
  gl_lds16(bS0 + (size_t)(half) * 131072 + 65536 + (t) * 128, ldsB##buf + (half) * 16384 + fo1); \
} while (0)

#define LDA(buf, qm) \
  _Pragma("unroll") for (int mtq = 0; mtq < 4; ++mtq) { \
    const int row_ = wr128 + (qm) * 64 + mtq * 16 + r; \
    af[mtq][0] = *(const bf16x8*)(ldsA##buf + row_ * 128 + lo0); \
    af[mtq][1] = *(const bf16x8*)(ldsA##buf + row_ * 128 + lo1); \
  }
#define LDB(buf, qn) \
  _Pragma("unroll") for (int ntq = 0; ntq < 2; ++ntq) { \
    const int row_ = wc64 + (qn) * 32 + ntq * 16 + r; \
    bf[ntq][0] = *(const bf16x8*)(ldsB##buf + row_ * 128 + lo0); \
    bf[ntq][1] = *(const bf16x8*)(ldsB##buf + row_ * 128 + lo1); \
  }

#define MM(qm, qn) \
  _Pragma("unroll") for (int mtq = 0; mtq < 4; ++mtq) \
    _Pragma("unroll") for (int ntq = 0; ntq < 2; ++ntq) { \
      acc[(qm)*4+mtq][(qn)*2+ntq] = MFMA16(af[mtq][0], bf[ntq][0], acc[(qm)*4+mtq][(qn)*2+ntq]); \
      acc[(qm)*4+mtq][(qn)*2+ntq] = MFMA16(af[mtq][1], bf[ntq][1], acc[(qm)*4+mtq][(qn)*2+ntq]); \
    }

#define MFMA_PHASE(qm, qn) do { \
  BARX(); WLGK(); \
  __builtin_amdgcn_s_setprio(1); \
  MM(qm, qn); \
  __builtin_amdgcn_s_setprio(0); \
} while (0)

__global__ __launch_bounds__(512, 2) void gemm8(
    const u16* __restrict__ A, const u16* __restrict__ Wf,
    const float* b0, const float* b1, const float* b2,
    u16* O0, u16* O1, u16* O2, float* OF, int qkv_mode)
{
  const int m0   = blockIdx.x * 256;
  const int by   = blockIdx.y;
  const int n0   = by * 256;
  const int sel  = by >> 1;
  const int ncol = (by & 1) * 256;

  __shared__ u16 As[2][256 * 64];   // 2 x 32 KB, 128-B rows
  __shared__ u16 Bs[2][256 * 64];   // 2 x 32 KB

  char* ldsA0 = (char*)&As[0][0];  char* ldsA1 = (char*)&As[1][0];
  char* ldsB0 = (char*)&Bs[0][0];  char* ldsB1 = (char*)&Bs[1][0];

  const int tid   = threadIdx.x;
  const int lane  = tid & 63;
  const int wv    = tid >> 6;
  const int r     = lane & 15;
  const int qd    = lane >> 4;
  const int wr128 = (wv >> 2) * 128;    // wave m-offset (0/128)
  const int wc64  = (wv & 3) * 64;      // wave n-offset (0..192)

  // Staging: half-tile = 128 rows x 128 B; thread t covers flat bytes t*16
  // and 8192+t*16.  Source 16B-granule pre-swizzled: g_src = g ^ (row&7).
  const int fo0  = tid * 16;
  const int fo1  = 8192 + tid * 16;
  const int cswz = ((tid & 7) ^ ((tid >> 3) & 7)) << 4;
  const char* aS0 = (const char*)A  + (size_t)(m0 + (tid >> 3)) * 1024 + cswz;
  const char* bS0 = (const char*)Wf + (size_t)(n0 + (tid >> 3)) * 1024 + cswz;

  // ds_read: granule (ks*4+qd) ^ (r&7)   (row&7 == r&7 for all frag rows)
  const int lo0 = ( qd      ^ (r & 7)) << 4;
  const int lo1 = ((4 + qd) ^ (r & 7)) << 4;

  f32x4  acc[8][4] = {};
  bf16x8 af[4][2], bf[2][2];

  // Prologue: tiles 0 (buf0) and 1 (buf1), 16 loads; wait tile0 (8 newest fly).
  STG_B(0, 0, 0); STG_B(0, 1, 0); STG_A(0, 0, 0); STG_A(0, 1, 0);
  STG_B(1, 0, 1); STG_B(1, 1, 1); STG_A(1, 0, 1); STG_A(1, 1, 1);
  VMW(8); BARX();

  #pragma unroll
  for (int i = 0; i < 4; ++i) {
    const int v = 2 * i + 1;          // K-tile in buf1 (phases 5-8)
    const int w = 2 * i + 2;          // next even K-tile -> buf0
    const int x2 = 2 * i + 3;         // next odd K-tile -> buf1

    // ---- K-tile u = 2i (buf0): phases 1-4 ----
    LDA(0, 0) LDB(0, 0)  STG_B(1, 1, v);
    MFMA_PHASE(0, 0);  BARX();

    LDA(0, 1)            STG_A(1, 0, v);
    MFMA_PHASE(1, 0);  BARX();

    LDB(0, 1)            STG_A(1, 1, v);
    MFMA_PHASE(1, 1);  BARX();

    LDA(0, 0)            if (i < 3) { STG_B(0, 0, w); }
    MFMA_PHASE(0, 1);
    if (i < 3) { VMW(2); } else { VMW(0); }
    BARX();

    // ---- K-tile v = 2i+1 (buf1): phases 5-8 ----
    LDA(1, 0) LDB(1, 0)  if (i < 3) { STG_B(0, 1, w); }
    MFMA_PHASE(0, 0);  BARX();

    LDA(1, 1)            if (i < 3) { STG_A(0, 0, w); }
    MFMA_PHASE(1, 0);  BARX();

    LDB(1, 1)            if (i < 3) { STG_A(0, 1, w); }
    MFMA_PHASE(1, 1);  BARX();

    LDA(1, 0)            if (i < 3) { STG_B(1, 0, x2); }
    MFMA_PHASE(0, 1);
    if (i < 3) { VMW(2); }
    BARX();
  }

  // ---- epilogue ----
  float bvv[4];
  const float* bp_ = (sel == 0) ? b0 : (sel == 1) ? b1 : b2;
  #pragma unroll
  for (int nt = 0; nt < 4; ++nt) bvv[nt] = bp_[ncol + wc64 + nt * 16 + r];

  if (qkv_mode) {
    u16* O = (sel == 0) ? O0 : (sel == 1) ? O1 : O2;
    #pragma unroll
    for (int mt = 0; mt < 8; ++mt) {
      #pragma unroll
      for (int rr = 0; rr < 4; ++rr) {
        const int m   = m0 + wr128 + mt * 16 + qd * 4 + rr;   // (b*T+t)*C + c
        const int b   = m / 1536;
        const int rem = m - b * 1536;
        const int t   = rem / 6;
        const int c   = rem - t * 6;
        #pragma unroll
        for (int nt = 0; nt < 4; ++nt) {
          const int colm = ncol + wc64 + nt * 16 + r;          // h*64 + d
          const int h = colm >> 6;
          const int d = colm & 63;
          const size_t addr = ((((size_t)b * 8 + h) * 6 + c) * 256 + t) * 64 + d;
          O[addr] = f2b(acc[mt][nt][rr] + bvv[nt]);
        }
      }
    }
  } else {
    #pragma unroll
    for (int mt = 0; mt < 8; ++mt) {
      #pragma unroll
      for (int rr = 0; rr < 4; ++rr) {
        const int m = m0 + wr128 + mt * 16 + qd * 4 + rr;
        #pragma unroll
        for (int nt = 0; nt < 4; ++nt)
          OF[(size_t)m * 512 + ncol + wc64 + nt * 16 + r] = acc[mt][nt][rr] + bvv[nt];
      }
    }
  }
}

// ---------------------------------------------------------------------------
// Causal attention, one block per (b,h,c).  512 threads = 8 waves.
// Wave w owns query tiles {w, 15-w}; keys in 2 super-chunks of 128.
// LDS = 18+17+18 = 53 KB.
// ---------------------------------------------------------------------------
__global__ __launch_bounds__(512, 2) void attn(
    const u16* __restrict__ q_ws, const u16* __restrict__ k_ws,
    const u16* __restrict__ v_ws, u16* __restrict__ y_ws)
{
  const int blk = blockIdx.x;            // (b*8 + h)*6 + c  (b slab-local)
  const int b   = blk / 48;
  const int h   = (blk / 6) % 8;
  const int c   = blk % 6;
  const size_t base = (size_t)blk * 256 * 64;

  __shared__ u16 Ks[128 * 72];           // 18 KB  K super-chunk, padded stride
  __shared__ u16 Vts[64 * 136];          // 17 KB  V^T super-chunk
  __shared__ u16 Ps[8][16 * 72];         // 18 KB  per-wave P tile

  const int tid  = threadIdx.x;
  const int lane = tid & 63;
  const int wv   = tid >> 6;
  const int r    = lane & 15;
  const int qd   = lane >> 4;

  const int tiles[2] = { wv, 15 - wv };

  bf16x8 qf[2][2];
  #pragma unroll
  for (int ti = 0; ti < 2; ++ti)
    #pragma unroll
    for (int kc = 0; kc < 2; ++kc)
      qf[ti][kc] = *(const bf16x8*)(q_ws + base +
                     (size_t)(tiles[ti] * 16 + r) * 64 + kc * 32 + qd * 8);

  f32x4 o_acc[2][4] = {};
  float l_acc[2][4] = {{0.f,0.f,0.f,0.f},{0.f,0.f,0.f,0.f}};

  for (int sc = 0; sc < 2; ++sc) {
    __syncthreads();
    #pragma unroll
    for (int it = 0; it < 2; ++it) {
      const int idx = it * 512 + tid;
      const int row = idx >> 3;
      const int c8  = idx & 7;
      *(bf16x8*)(Ks + row * 72 + c8 * 8) =
          *(const bf16x8*)(k_ws + base + (size_t)(sc * 128 + row) * 64 + c8 * 8);
    }
    {
      const int jl = tid & 127;
      const int d0 = (tid >> 7) * 16;
      #pragma unroll
      for (int dd = 0; dd < 16; dd += 8) {
        bf16x8 vv = *(const bf16x8*)(v_ws + base +
                       (size_t)(sc * 128 + jl) * 64 + d0 + dd);
        #pragma unroll
        for (int e = 0; e < 8; ++e)
          Vts[(d0 + dd + e) * 136 + jl] = ((u16*)&vv)[e];
      }
    }
    __syncthreads();

    #pragma unroll
    for (int ti = 0; ti < 2; ++ti) {
      const int mt  = tiles[ti];
      const int i0  = mt * 16;
      const int nch = (mt >> 2) + 1;
      #pragma unroll
      for (int jcl = 0; jcl < 2; ++jcl) {
        const int jc = sc * 2 + jcl;
        if (jc >= nch) continue;            // wave-uniform skip
        const int j0l = jcl * 64;
        const int j0g = sc * 128 + j0l;

        f32x4 s[4] = {};
        #pragma unroll
        for (int nt = 0; nt < 4; ++nt)
          #pragma unroll
          for (int kc = 0; kc < 2; ++kc) {
            bf16x8 kf = *(const bf16x8*)(Ks + (j0l + nt * 16 + r) * 72 +
                                         kc * 32 + qd * 8);
            s[nt] = MFMA16(qf[ti][kc], kf, s[nt]);
          }

        #pragma unroll
        for (int nt = 0; nt < 4; ++nt)
          #pragma unroll
          for (int rr = 0; rr < 4; ++rr) {
            const int i = i0 + qd * 4 + rr;
            const int j = j0g + nt * 16 + r;
            float p = __builtin_exp2f(fminf(s[nt][rr], 500.f) *
                                      0.1803368801111244f);  // *(1/8)*log2(e)
            if (j > i) p = 0.f;
            l_acc[ti][rr] += p;
            Ps[wv][(qd * 4 + rr) * 72 + nt * 16 + r] = f2b(p);
          }
        asm volatile("s_waitcnt lgkmcnt(0)" ::: "memory");

        bf16x8 pf[2];
        #pragma unroll
        for (int kc = 0; kc < 2; ++kc)
          pf[kc] = *(const bf16x8*)(Ps[wv] + r * 72 + kc * 32 + qd * 8);
        #pragma unroll
        for (int ntd = 0; ntd < 4; ++ntd)
          #pragma unroll
          for (int kc = 0; kc < 2; ++kc) {
            bf16x8 vf = *(const bf16x8*)(Vts + (ntd * 16 + r) * 136 +
                                         j0l + kc * 32 + qd * 8);
            o_acc[ti][ntd] = MFMA16(pf[kc], vf, o_acc[ti][ntd]);
          }
      }
    }
  }

  const size_t obase = ((size_t)b * 256) * 3072 + h * 384 + c * 64;
  #pragma unroll
  for (int ti = 0; ti < 2; ++ti) {
    const int i0 = tiles[ti] * 16;
    float linv[4];
    #pragma unroll
    for (int rr = 0; rr < 4; ++rr) {
      float sum = l_acc[ti][rr];
      sum += __shfl_xor(sum, 1, 16);
      sum += __shfl_xor(sum, 2, 16);
      sum += __shfl_xor(sum, 4, 16);
      sum += __shfl_xor(sum, 8, 16);
      linv[rr] = 1.f / sum;
    }
    #pragma unroll
    for (int ntd = 0; ntd < 4; ++ntd)
      #pragma unroll
      for (int rr = 0; rr < 4; ++rr) {
        const int t = i0 + qd * 4 + rr;
        const int d = ntd * 16 + r;
        y_ws[obase + (size_t)t * 3072 + d] = f2b(o_acc[ti][ntd][rr] * linv[rr]);
      }
  }
}

// ---------------------------------------------------------------------------
extern "C" void kernel_launch(void* const* d_in, const int* in_sizes, int n_in,
                              void* d_out, int out_size, void* d_ws, size_t ws_size,
                              hipStream_t stream) {
  const float* x  = (const float*)d_in[0];
  const float* Wq = (const float*)d_in[1];
  const float* bq = (const float*)d_in[2];
  const float* Wk = (const float*)d_in[3];
  const float* bk = (const float*)d_in[4];
  const float* Wv = (const float*)d_in[5];
  const float* bv = (const float*)d_in[6];
  const float* Wp = (const float*)d_in[7];
  const float* bp = (const float*)d_in[8];
  float* out = (float*)d_out;                        // fp32 output

  const size_t PER_B = 256 * 6 * 512;       // 786432 elems per tensor per batch
  const size_t WSEG  = 4 * 262144;          // converted weights: Wq,Wk,Wv,Wp

  int NB = 16;
  while (NB > 1 && (WSEG + (size_t)5 * NB * PER_B) * 2 > ws_size) NB >>= 1;

  u16* wbf = (u16*)d_ws;
  u16* Wqb = wbf;                            // fused [Wq;Wk;Wv] = 1536 x 512
  u16* Wpb = wbf + 3 * 262144;

  const size_t slab = (size_t)NB * PER_B;
  u16* xbf  = wbf + WSEG;
  u16* q_ws = xbf + slab;
  u16* k_ws = q_ws + slab;
  u16* v_ws = k_ws + slab;
  u16* y_ws = v_ws + slab;

  cvt_w<<<dim3(256, 4), 256, 0, stream>>>(Wq, Wk, Wv, Wp, wbf);

  const int nslab = 16 / NB;
  for (int s = 0; s < nslab; ++s) {
    const float* x_s  = x   + (size_t)s * NB * PER_B;
    float*      out_s = out + (size_t)s * NB * PER_B;
    cvt_x<<<dim3(NB * 768), 256, 0, stream>>>(x_s, xbf);
    gemm8<<<dim3(NB * 6, 6), 512, 0, stream>>>(
        xbf, Wqb, bq, bk, bv, q_ws, k_ws, v_ws, nullptr, 1);
    attn<<<dim3(NB * 48), 512, 0, stream>>>(q_ws, k_ws, v_ws, y_ws);
    gemm8<<<dim3(NB * 6, 2), 512, 0, stream>>>(
        y_ws, Wpb, bp, bp, bp, nullptr, nullptr, nullptr, out_s, 0);
  }
}

// Round 4
// 202.053 us; speedup vs baseline: 1.1358x; 1.1358x over previous
//
#include <hip/hip_runtime.h>

// B=16, T=256, C=6, E=512, H=8, hd=64.
// Inputs fp32; OUTPUT fp32. Compute in bf16 MFMA; biases added in fp32.
//
// Round 8: FUSE QKV-GEMM + attention into one kernel (one block per (b,h,c)).
// Rationale: three different GEMM schedules all pinned at 21-25% MfmaUtil ->
// per-block fixed costs dominate at K=512, so remove whole-pipeline costs
// instead: the 73.7 MB q/k/v scatter-store + 75 MB attn re-read + V^T
// restaging + one dispatch all disappear. GEMM inner loop, swizzle, attn
// math are the round-0 proven code paths verbatim; numerics unchanged.

typedef unsigned short u16;
typedef short bf16x8 __attribute__((ext_vector_type(8)));   // 8 bf16 = 4 VGPRs
typedef float f32x4 __attribute__((ext_vector_type(4)));
typedef u16 u16x4 __attribute__((ext_vector_type(4)));

#define MFMA16(a, b, c) __builtin_amdgcn_mfma_f32_16x16x32_bf16((a), (b), (c), 0, 0, 0)

__device__ __forceinline__ u16 f2b(float f) {
  union { float f; unsigned u; } v; v.f = f;
  unsigned r = v.u + 0x7fffu + ((v.u >> 16) & 1u);   // RNE (finite inputs)
  return (u16)(r >> 16);
}
__device__ __forceinline__ void gl_lds16(const void* g, void* l) {
  __builtin_amdgcn_global_load_lds(
      (const __attribute__((address_space(1))) void*)g,
      (__attribute__((address_space(3))) void*)l, 16, 0, 0);
}

// ---------------------------------------------------------------------------
// fp32 -> bf16 converters
// ---------------------------------------------------------------------------
__global__ void cvt_w(const float* W0, const float* W1, const float* W2,
                      const float* W3, u16* dst) {
  const float* src = (blockIdx.y == 0) ? W0 : (blockIdx.y == 1) ? W1
                   : (blockIdx.y == 2) ? W2 : W3;
  const int idx = (blockIdx.x * 256 + threadIdx.x) * 4;
  f32x4 v = *(const f32x4*)(src + idx);
  u16x4 o; o.x = f2b(v.x); o.y = f2b(v.y); o.z = f2b(v.z); o.w = f2b(v.w);
  *(u16x4*)(dst + (size_t)blockIdx.y * 262144 + idx) = o;
}

__global__ void cvt_x(const float* __restrict__ src, u16* __restrict__ dst) {
  const size_t idx = ((size_t)blockIdx.x * 256 + threadIdx.x) * 4;
  f32x4 v = *(const f32x4*)(src + idx);
  u16x4 o; o.x = f2b(v.x); o.y = f2b(v.y); o.z = f2b(v.z); o.w = f2b(v.w);
  *(u16x4*)(dst + idx) = o;
}

// ---------------------------------------------------------------------------
// Fused QKV + causal attention.  One block per (b,h,c); 512 thr = 8 waves.
// Wave w owns t-tiles {w, 15-w} (16 rows each) of Q,K,V and of the attention.
// Phase 1: GEMM  Q/K/V[256x64] = X[256x512] x W{q,k,v}[h-slice 64x512]^T,
//   staged K-chunks (BK=32) of X (256 rows) + W (3x64 rows) in one dbuf LDS
//   buffer, round-0 chunk swizzle, 24 MFMA/step, one barrier/step.
// Phase 2: epilogue K->Ks (pad 72), V->Vts transposed (pad 264), bias fp32.
// Phase 3: attention (round-0 attn verbatim, no staging; Q bounced via a
//   per-wave LDS scratch that is afterwards reused as the P tile).
// LDS: 2x28 KB staging + 36 KB Ks + 33 KB Vts + 18 KB Q/P = 143 KB.
// ---------------------------------------------------------------------------
#define STAGE(k, bi) do { \
  _Pragma("unroll") \
  for (int j_ = 0; j_ < 4; ++j_) \
    if (j_ < 3 || tid < 256) \
      gl_lds16(gsrc[j_] + (k) * 64, (char*)Ss[bi] + fl[j_]); \
} while (0)

__global__ __launch_bounds__(512, 2) void qkv_attn(
    const u16* __restrict__ xbf, const u16* __restrict__ wbf,
    const float* __restrict__ bq, const float* __restrict__ bk,
    const float* __restrict__ bv, u16* __restrict__ y_ws)
{
  const int blk = blockIdx.x;            // (b*8 + h)*6 + c  (b slab-local)
  const int b   = blk / 48;
  const int h   = (blk / 6) % 8;
  const int c   = blk % 6;

  __shared__ u16 Ss[2][448 * 32];        // 2 x 28 KB: rows 0..255 = X t-rows,
                                         // rows 256..447 = W rows (tau*64+n)
  __shared__ u16 Ks[256 * 72];           // 36 KB
  __shared__ u16 Vts[64 * 264];          // 33 KB, V transposed [d][t]
  __shared__ u16 Qs[8][16 * 72];         // 18 KB, per-wave Q then P scratch

  const int tid  = threadIdx.x;
  const int lane = tid & 63;
  const int wv   = tid >> 6;
  const int r    = lane & 15;
  const int qd   = lane >> 4;
  const int tiles[2] = { wv, 15 - wv };

  // ---- staging source pointers (round-0 chunk swizzle: stored chunk q holds
  // global chunk (q - row>>1)&3; read side uses (qd + row>>1)&3) ----
  const char* gsrc[4]; int fl[4];
  #pragma unroll
  for (int j = 0; j < 4; ++j) {
    const int idx  = j * 512 + tid;
    const int flat = idx * 16;
    const int row  = flat >> 6;                       // 64 B per row
    const int gc   = (((flat >> 4) & 3) - (row >> 1)) & 3;
    fl[j] = flat;
    if (row < 256) {
      gsrc[j] = (const char*)xbf +
                ((size_t)(b * 256 + row) * 6 + c) * 1024 + gc * 16;
    } else {
      const int wr  = row - 256;
      const int tau = (wr >> 6) & 3;                  // masked for inactive lanes
      const int n   = wr & 63;
      gsrc[j] = (const char*)wbf + (size_t)tau * 524288 +
                (size_t)(h * 64 + n) * 1024 + gc * 16;
    }
  }

  // fragment LDS byte offsets (loop-invariant)
  int aoff[2], boff[3][4];
  #pragma unroll
  for (int ti = 0; ti < 2; ++ti) {
    const int row = tiles[ti] * 16 + r;
    aoff[ti] = row * 64 + ((qd + (row >> 1)) & 3) * 16;
  }
  #pragma unroll
  for (int tau = 0; tau < 3; ++tau)
    #pragma unroll
    for (int nt = 0; nt < 4; ++nt) {
      const int row = 256 + tau * 64 + nt * 16 + r;
      boff[tau][nt] = row * 64 + ((qd + (row >> 1)) & 3) * 16;
    }

  f32x4 acc[3][2][4] = {};   // [q,k,v][tile][ntile]

  // ---- Phase 1: GEMM over K=512, BK=32, double-buffered ----
  STAGE(0, 0);
  __syncthreads();

  #pragma unroll 2
  for (int kt = 0; kt < 16; ++kt) {
    const int bi = kt & 1;
    if (kt < 15) STAGE(kt + 1, bi ^ 1);

    bf16x8 af[2], bfr[3][4];
    #pragma unroll
    for (int ti = 0; ti < 2; ++ti)
      af[ti] = *(const bf16x8*)((const char*)Ss[bi] + aoff[ti]);
    #pragma unroll
    for (int tau = 0; tau < 3; ++tau)
      #pragma unroll
      for (int nt = 0; nt < 4; ++nt)
        bfr[tau][nt] = *(const bf16x8*)((const char*)Ss[bi] + boff[tau][nt]);

    #pragma unroll
    for (int tau = 0; tau < 3; ++tau)
      #pragma unroll
      for (int ti = 0; ti < 2; ++ti)
        #pragma unroll
        for (int nt = 0; nt < 4; ++nt)
          acc[tau][ti][nt] = MFMA16(af[ti], bfr[tau][nt], acc[tau][ti][nt]);

    __syncthreads();   // drains staged kt+1; guards buffer reuse
  }

  // ---- Phase 2: K,V epilogue to LDS (bias in fp32, then f2b) ----
  float bqv[4], bkv[4], bvv[4];
  #pragma unroll
  for (int nt = 0; nt < 4; ++nt) {
    const int col = h * 64 + nt * 16 + r;
    bqv[nt] = bq[col]; bkv[nt] = bk[col]; bvv[nt] = bv[col];
  }
  #pragma unroll
  for (int ti = 0; ti < 2; ++ti)
    #pragma unroll
    for (int nt = 0; nt < 4; ++nt)
      #pragma unroll
      for (int rr = 0; rr < 4; ++rr) {
        const int trow = tiles[ti] * 16 + qd * 4 + rr;
        const int col  = nt * 16 + r;
        Ks[trow * 72 + col]  = f2b(acc[1][ti][nt][rr] + bkv[nt]);
        Vts[col * 264 + trow] = f2b(acc[2][ti][nt][rr] + bvv[nt]);
      }
  __syncthreads();

  // ---- Phase 3: causal attention (round-0 attn inner loop) ----
  f32x4 o_acc[2][4] = {};
  float l_acc[2][4] = {{0.f,0.f,0.f,0.f},{0.f,0.f,0.f,0.f}};

  #pragma unroll
  for (int ti = 0; ti < 2; ++ti) {
    const int mt  = tiles[ti];
    const int i0  = mt * 16;
    const int nch = (mt >> 2) + 1;

    // Q bounce through per-wave scratch (wave-local; DS ops are in-order)
    #pragma unroll
    for (int nt = 0; nt < 4; ++nt)
      #pragma unroll
      for (int rr = 0; rr < 4; ++rr)
        Qs[wv][(qd * 4 + rr) * 72 + nt * 16 + r] =
            f2b(acc[0][ti][nt][rr] + bqv[nt]);
    asm volatile("s_waitcnt lgkmcnt(0)" ::: "memory");

    bf16x8 qf[2];
    #pragma unroll
    for (int kc = 0; kc < 2; ++kc)
      qf[kc] = *(const bf16x8*)(Qs[wv] + r * 72 + kc * 32 + qd * 8);
    asm volatile("s_waitcnt lgkmcnt(0)" ::: "memory");

    for (int jc = 0; jc < nch; ++jc) {   // wave-uniform chunk loop
      const int j0 = jc * 64;

      f32x4 s[4] = {};
      #pragma unroll
      for (int nt = 0; nt < 4; ++nt)
        #pragma unroll
        for (int kc = 0; kc < 2; ++kc) {
          bf16x8 kf = *(const bf16x8*)(Ks + (j0 + nt * 16 + r) * 72 +
                                       kc * 32 + qd * 8);
          s[nt] = MFMA16(qf[kc], kf, s[nt]);
        }

      #pragma unroll
      for (int nt = 0; nt < 4; ++nt)
        #pragma unroll
        for (int rr = 0; rr < 4; ++rr) {
          const int i = i0 + qd * 4 + rr;
          const int j = j0 + nt * 16 + r;
          float p = __builtin_exp2f(fminf(s[nt][rr], 500.f) *
                                    0.1803368801111244f);  // *(1/8)*log2(e)
          if (j > i) p = 0.f;
          l_acc[ti][rr] += p;
          Qs[wv][(qd * 4 + rr) * 72 + nt * 16 + r] = f2b(p);
        }
      asm volatile("s_waitcnt lgkmcnt(0)" ::: "memory");

      bf16x8 pf[2];
      #pragma unroll
      for (int kc = 0; kc < 2; ++kc)
        pf[kc] = *(const bf16x8*)(Qs[wv] + r * 72 + kc * 32 + qd * 8);
      #pragma unroll
      for (int ntd = 0; ntd < 4; ++ntd)
        #pragma unroll
        for (int kc = 0; kc < 2; ++kc) {
          bf16x8 vf = *(const bf16x8*)(Vts + (ntd * 16 + r) * 264 +
                                       j0 + kc * 32 + qd * 8);
          o_acc[ti][ntd] = MFMA16(pf[kc], vf, o_acc[ti][ntd]);
        }
    }
  }

  // ---- output: y layout [b][t][h][c][d] (faithful to the torch reshape) ----
  const size_t obase = ((size_t)b * 256) * 3072 + h * 384 + c * 64;
  #pragma unroll
  for (int ti = 0; ti < 2; ++ti) {
    const int i0 = tiles[ti] * 16;
    float linv[4];
    #pragma unroll
    for (int rr = 0; rr < 4; ++rr) {
      float sum = l_acc[ti][rr];
      sum += __shfl_xor(sum, 1, 16);
      sum += __shfl_xor(sum, 2, 16);
      sum += __shfl_xor(sum, 4, 16);
      sum += __shfl_xor(sum, 8, 16);
      linv[rr] = 1.f / sum;
    }
    #pragma unroll
    for (int ntd = 0; ntd < 4; ++ntd)
      #pragma unroll
      for (int rr = 0; rr < 4; ++rr) {
        const int t = i0 + qd * 4 + rr;
        const int d = ntd * 16 + r;
        y_ws[obase + (size_t)t * 3072 + d] = f2b(o_acc[ti][ntd][rr] * linv[rr]);
      }
  }
}

// ---------------------------------------------------------------------------
// BT-GEMM (round-0 verbatim, used for the output projection only).
// ---------------------------------------------------------------------------
__global__ __launch_bounds__(256, 3) void gemm_bt(
    const u16* __restrict__ A,
    const u16* W0, const u16* W1, const u16* W2,
    const float* bs0, const float* bs1, const float* bs2,
    u16* O0, u16* O1, u16* O2,
    float* OF,
    int qkv_mode)
{
  const int z = blockIdx.z;
  const u16* W    = (z == 0) ? W0 : (z == 1) ? W1 : W2;
  const float* bs = (z == 0) ? bs0 : (z == 1) ? bs1 : bs2;
  u16* O          = (z == 0) ? O0 : (z == 1) ? O1 : O2;

  const int m0 = blockIdx.x * 128;
  const int n0 = blockIdx.y * 128;

  __shared__ u16 As[128 * 32];   // 8 KB, 64B rows, chunk swizzle (q + (row>>1)) & 3
  __shared__ u16 Bs[128 * 32];

  const int tid  = threadIdx.x;
  const int lane = tid & 63;
  const int wv   = tid >> 6;
  const int r    = lane & 15;
  const int qd   = lane >> 4;
  const int wm   = (wv & 1) * 64;
  const int wn   = (wv >> 1) * 64;

  f32x4 acc[4][4] = {};

  for (int k0 = 0; k0 < 512; k0 += 32) {
    __syncthreads();
    #pragma unroll
    for (int it = 0; it < 2; ++it) {
      const int flat = (it * 256 + tid) * 16;       // byte offset in 8KB tile
      const int row  = flat >> 6;                   // 64 B per row
      const int swc  = (flat >> 4) & 3;
      const int gc   = (swc - (row >> 1)) & 3;      // un-swizzle for global side
      gl_lds16((const char*)A + (size_t)(m0 + row) * 1024 + k0 * 2 + gc * 16,
               (char*)As + flat);
      gl_lds16((const char*)W + (size_t)(n0 + row) * 1024 + k0 * 2 + gc * 16,
               (char*)Bs + flat);
    }
    __syncthreads();

    bf16x8 af[4], bf[4];
    #pragma unroll
    for (int mt = 0; mt < 4; ++mt) {
      const int row = wm + mt * 16 + r;
      const int sw  = (qd + (row >> 1)) & 3;
      af[mt] = *(const bf16x8*)((const char*)As + row * 64 + sw * 16);
    }
    #pragma unroll
    for (int nt = 0; nt < 4; ++nt) {
      const int row = wn + nt * 16 + r;
      const int sw  = (qd + (row >> 1)) & 3;
      bf[nt] = *(const bf16x8*)((const char*)Bs + row * 64 + sw * 16);
    }
    #pragma unroll
    for (int mt = 0; mt < 4; ++mt)
      #pragma unroll
      for (int nt = 0; nt < 4; ++nt)
        acc[mt][nt] = MFMA16(af[mt], bf[nt], acc[mt][nt]);
  }

  float bv[4];
  #pragma unroll
  for (int nt = 0; nt < 4; ++nt) bv[nt] = bs[n0 + wn + nt * 16 + r];

  if (qkv_mode) {
    #pragma unroll
    for (int mt = 0; mt < 4; ++mt) {
      #pragma unroll
      for (int rr = 0; rr < 4; ++rr) {
        const int m   = m0 + wm + mt * 16 + qd * 4 + rr;   // (b*T+t)*C + c
        const int b   = m / 1536;
        const int rem = m - b * 1536;
        const int t   = rem / 6;
        const int c   = rem - t * 6;
        #pragma unroll
        for (int nt = 0; nt < 4; ++nt) {
          const int f = n0 + wn + nt * 16 + r;             // h*64 + d
          const int hh = f >> 6;
          const int d = f & 63;
          const size_t addr = ((((size_t)b * 8 + hh) * 6 + c) * 256 + t) * 64 + d;
          O[addr] = f2b(acc[mt][nt][rr] + bv[nt]);
        }
      }
    }
  } else {
    #pragma unroll
    for (int mt = 0; mt < 4; ++mt) {
      #pragma unroll
      for (int rr = 0; rr < 4; ++rr) {
        const int m = m0 + wm + mt * 16 + qd * 4 + rr;
        #pragma unroll
        for (int nt = 0; nt < 4; ++nt) {
          const int f = n0 + wn + nt * 16 + r;
          OF[(size_t)m * 512 + f] = acc[mt][nt][rr] + bv[nt];   // fp32 output
        }
      }
    }
  }
}

// ---------------------------------------------------------------------------
extern "C" void kernel_launch(void* const* d_in, const int* in_sizes, int n_in,
                              void* d_out, int out_size, void* d_ws, size_t ws_size,
                              hipStream_t stream) {
  const float* x  = (const float*)d_in[0];
  const float* Wq = (const float*)d_in[1];
  const float* bq = (const float*)d_in[2];
  const float* Wk = (const float*)d_in[3];
  const float* bk = (const float*)d_in[4];
  const float* Wv = (const float*)d_in[5];
  const float* bv = (const float*)d_in[6];
  const float* Wp = (const float*)d_in[7];
  const float* bp = (const float*)d_in[8];
  float* out = (float*)d_out;                        // fp32 output

  const size_t PER_B = 256 * 6 * 512;       // 786432 elems per tensor per batch
  const size_t WSEG  = 4 * 262144;          // converted weights: Wq,Wk,Wv,Wp

  int NB = 16;
  while (NB > 1 && (WSEG + (size_t)2 * NB * PER_B) * 2 > ws_size) NB >>= 1;

  u16* wbf = (u16*)d_ws;                    // Wq | Wk | Wv | Wp (bf16)
  u16* Wpb = wbf + 3 * 262144;

  const size_t slab = (size_t)NB * PER_B;
  u16* xbf  = wbf + WSEG;
  u16* y_ws = xbf + slab;

  cvt_w<<<dim3(256, 4), 256, 0, stream>>>(Wq, Wk, Wv, Wp, wbf);

  const int nslab = 16 / NB;
  for (int s = 0; s < nslab; ++s) {
    const float* x_s  = x   + (size_t)s * NB * PER_B;
    float*      out_s = out + (size_t)s * NB * PER_B;
    cvt_x<<<dim3(NB * 768), 256, 0, stream>>>(x_s, xbf);
    qkv_attn<<<dim3(NB * 48), 512, 0, stream>>>(xbf, wbf, bq, bk, bv, y_ws);
    gemm_bt<<<dim3(NB * 12, 4, 1), 256, 0, stream>>>(
        y_ws, Wpb, Wpb, Wpb, bp, bp, bp, nullptr, nullptr, nullptr, out_s, 0);
  }
}

// Round 5
// 198.757 us; speedup vs baseline: 1.1546x; 1.0166x over previous
//
#include <hip/hip_runtime.h>

// B=16, T=256, C=6, E=512, H=8, hd=64.
// Inputs fp32; OUTPUT fp32. Compute in bf16 MFMA; biases added in fp32.
//
// Round 9: same fused qkv_attn as round 8, but LDS shrunk 143 KB -> 80 KB so
// TWO blocks fit per CU (160 KB / 80 KB):
//  - staging buffers (56 KB, Phase 1 only) alias the K/V region (Phases 2-3
//    disjoint, separated by the loop-end __syncthreads).
//  - pads replaced by XOR swizzle (granule ^= row&7) on Ks (128-B rows),
//    Vts (512-B rows), Qs (128-B rows); write+read sides verified to
//    round-trip; lanes r / r+8 share a bank -> 2-way (free).
// Occupancy 19.6% -> ~2x; 768 blocks run in 1.5 rounds instead of 3.

typedef unsigned short u16;
typedef short bf16x8 __attribute__((ext_vector_type(8)));   // 8 bf16 = 4 VGPRs
typedef float f32x4 __attribute__((ext_vector_type(4)));
typedef u16 u16x4 __attribute__((ext_vector_type(4)));

#define MFMA16(a, b, c) __builtin_amdgcn_mfma_f32_16x16x32_bf16((a), (b), (c), 0, 0, 0)

__device__ __forceinline__ u16 f2b(float f) {
  union { float f; unsigned u; } v; v.f = f;
  unsigned r = v.u + 0x7fffu + ((v.u >> 16) & 1u);   // RNE (finite inputs)
  return (u16)(r >> 16);
}
__device__ __forceinline__ void gl_lds16(const void* g, void* l) {
  __builtin_amdgcn_global_load_lds(
      (const __attribute__((address_space(1))) void*)g,
      (__attribute__((address_space(3))) void*)l, 16, 0, 0);
}

// ---------------------------------------------------------------------------
// fp32 -> bf16 converters
// ---------------------------------------------------------------------------
__global__ void cvt_w(const float* W0, const float* W1, const float* W2,
                      const float* W3, u16* dst) {
  const float* src = (blockIdx.y == 0) ? W0 : (blockIdx.y == 1) ? W1
                   : (blockIdx.y == 2) ? W2 : W3;
  const int idx = (blockIdx.x * 256 + threadIdx.x) * 4;
  f32x4 v = *(const f32x4*)(src + idx);
  u16x4 o; o.x = f2b(v.x); o.y = f2b(v.y); o.z = f2b(v.z); o.w = f2b(v.w);
  *(u16x4*)(dst + (size_t)blockIdx.y * 262144 + idx) = o;
}

__global__ void cvt_x(const float* __restrict__ src, u16* __restrict__ dst) {
  const size_t idx = ((size_t)blockIdx.x * 256 + threadIdx.x) * 4;
  f32x4 v = *(const f32x4*)(src + idx);
  u16x4 o; o.x = f2b(v.x); o.y = f2b(v.y); o.z = f2b(v.z); o.w = f2b(v.w);
  *(u16x4*)(dst + idx) = o;
}

// ---------------------------------------------------------------------------
// Fused QKV + causal attention.  One block per (b,h,c); 512 thr = 8 waves.
// Wave w owns t-tiles {w, 15-w}.  LDS = 80 KB total:
//   bytes [    0, 32768)  Ks  256 rows x 128 B  (XOR-swizzled)
//   bytes [32768, 65536)  Vts  64 rows x 512 B  (V transposed, XOR-swizzled)
//   bytes [65536, 81920)  Qs   8 waves x 16 rows x 128 B (Q then P scratch)
//   Phase-1 staging: 2 x 28 KB at bytes [0, 57344), aliases Ks+Vts.
// ---------------------------------------------------------------------------
#define STAGE(k, bi) do { \
  _Pragma("unroll") \
  for (int j_ = 0; j_ < 4; ++j_) \
    if (j_ < 3 || tid < 256) \
      gl_lds16(gsrc[j_] + (k) * 64, Sb + (bi) * 28672 + fl[j_]); \
} while (0)

__global__ __launch_bounds__(512, 2) void qkv_attn(
    const u16* __restrict__ xbf, const u16* __restrict__ wbf,
    const float* __restrict__ bq, const float* __restrict__ bk,
    const float* __restrict__ bv, u16* __restrict__ y_ws)
{
  const int blk = blockIdx.x;            // (b*8 + h)*6 + c  (b slab-local)
  const int b   = blk / 48;
  const int h   = (blk / 6) % 8;
  const int c   = blk % 6;

  __shared__ u16 LDS[40960];             // 80 KB
  char* Ksb  = (char*)LDS;               // Ks base
  char* Vtsb = (char*)LDS + 32768;       // Vts base
  char* Sb   = (char*)LDS;               // staging base (aliases Ks+Vts)

  const int tid  = threadIdx.x;
  const int lane = tid & 63;
  const int wv   = tid >> 6;
  const int r    = lane & 15;
  const int qd   = lane >> 4;
  const int tiles[2] = { wv, 15 - wv };
  char* Qw = (char*)LDS + 65536 + wv * 2048;   // per-wave 16 x 128 B

  // ---- staging source pointers (round-0 chunk swizzle: stored chunk q holds
  // global chunk (q - row>>1)&3; read side uses (qd + row>>1)&3) ----
  const char* gsrc[4]; int fl[4];
  #pragma unroll
  for (int j = 0; j < 4; ++j) {
    const int idx  = j * 512 + tid;
    const int flat = idx * 16;
    const int row  = flat >> 6;                       // 64 B per row
    const int gc   = (((flat >> 4) & 3) - (row >> 1)) & 3;
    fl[j] = flat;
    if (row < 256) {
      gsrc[j] = (const char*)xbf +
                ((size_t)(b * 256 + row) * 6 + c) * 1024 + gc * 16;
    } else {
      const int wr  = row - 256;
      const int tau = (wr >> 6) & 3;                  // masked for inactive lanes
      const int n   = wr & 63;
      gsrc[j] = (const char*)wbf + (size_t)tau * 524288 +
                (size_t)(h * 64 + n) * 1024 + gc * 16;
    }
  }

  // fragment LDS byte offsets within one staging buffer (loop-invariant)
  int aoff[2], boff[3][4];
  #pragma unroll
  for (int ti = 0; ti < 2; ++ti) {
    const int row = tiles[ti] * 16 + r;
    aoff[ti] = row * 64 + ((qd + (row >> 1)) & 3) * 16;
  }
  #pragma unroll
  for (int tau = 0; tau < 3; ++tau)
    #pragma unroll
    for (int nt = 0; nt < 4; ++nt) {
      const int row = 256 + tau * 64 + nt * 16 + r;
      boff[tau][nt] = row * 64 + ((qd + (row >> 1)) & 3) * 16;
    }

  f32x4 acc[3][2][4] = {};   // [q,k,v][tile][ntile]

  // ---- Phase 1: GEMM over K=512, BK=32, double-buffered ----
  STAGE(0, 0);
  __syncthreads();

  #pragma unroll 2
  for (int kt = 0; kt < 16; ++kt) {
    const int bi = kt & 1;
    if (kt < 15) STAGE(kt + 1, bi ^ 1);

    bf16x8 af[2], bfr[3][4];
    #pragma unroll
    for (int ti = 0; ti < 2; ++ti)
      af[ti] = *(const bf16x8*)(Sb + bi * 28672 + aoff[ti]);
    #pragma unroll
    for (int tau = 0; tau < 3; ++tau)
      #pragma unroll
      for (int nt = 0; nt < 4; ++nt)
        bfr[tau][nt] = *(const bf16x8*)(Sb + bi * 28672 + boff[tau][nt]);

    #pragma unroll
    for (int tau = 0; tau < 3; ++tau)
      #pragma unroll
      for (int ti = 0; ti < 2; ++ti)
        #pragma unroll
        for (int nt = 0; nt < 4; ++nt)
          acc[tau][ti][nt] = MFMA16(af[ti], bfr[tau][nt], acc[tau][ti][nt]);

    __syncthreads();   // drains staged kt+1; guards buffer reuse
  }
  // Phase-1 done: staging region free for Ks/Vts.

  // ---- Phase 2: K,V epilogue to LDS (bias in fp32, then f2b) ----
  float bqv[4], bkv[4], bvv[4];
  #pragma unroll
  for (int nt = 0; nt < 4; ++nt) {
    const int col = h * 64 + nt * 16 + r;
    bqv[nt] = bq[col]; bkv[nt] = bk[col]; bvv[nt] = bv[col];
  }
  #pragma unroll
  for (int ti = 0; ti < 2; ++ti)
    #pragma unroll
    for (int nt = 0; nt < 4; ++nt)
      #pragma unroll
      for (int rr = 0; rr < 4; ++rr) {
        const int trow = tiles[ti] * 16 + qd * 4 + rr;
        // Ks[trow][nt*16+r], 128-B rows, granule ^= trow&7
        const int kb = trow * 128 +
            ((((nt * 2 + (r >> 3)) ^ (trow & 7)) << 4)) + (r & 7) * 2;
        *(u16*)(Ksb + kb) = f2b(acc[1][ti][nt][rr] + bkv[nt]);
        // Vts[d = nt*16+r][t = trow], 512-B rows, granule ^= d&7 (= r&7)
        const int vb = (nt * 16 + r) * 512 +
            ((((trow >> 3) ^ (r & 7)) << 4)) + (trow & 7) * 2;
        *(u16*)(Vtsb + vb) = f2b(acc[2][ti][nt][rr] + bvv[nt]);
      }
  __syncthreads();

  // ---- Phase 3: causal attention ----
  const int lo0 = (( qd      ) ^ (r & 7)) << 4;   // granule kc*4+qd, kc=0
  const int lo1 = ((4 + qd) ^ (r & 7)) << 4;      // kc=1

  f32x4 o_acc[2][4] = {};
  float l_acc[2][4] = {{0.f,0.f,0.f,0.f},{0.f,0.f,0.f,0.f}};

  #pragma unroll
  for (int ti = 0; ti < 2; ++ti) {
    const int mt  = tiles[ti];
    const int i0  = mt * 16;
    const int nch = (mt >> 2) + 1;

    // Q bounce through per-wave scratch (wave-local; DS ops are in-order)
    #pragma unroll
    for (int nt = 0; nt < 4; ++nt)
      #pragma unroll
      for (int rr = 0; rr < 4; ++rr) {
        const int prow = qd * 4 + rr;
        const int qb = prow * 128 +
            (((nt * 2 + (r >> 3)) ^ (prow & 7)) << 4) + (r & 7) * 2;
        *(u16*)(Qw + qb) = f2b(acc[0][ti][nt][rr] + bqv[nt]);
      }
    asm volatile("s_waitcnt lgkmcnt(0)" ::: "memory");

    bf16x8 qf[2];
    qf[0] = *(const bf16x8*)(Qw + r * 128 + lo0);
    qf[1] = *(const bf16x8*)(Qw + r * 128 + lo1);
    asm volatile("s_waitcnt lgkmcnt(0)" ::: "memory");

    for (int jc = 0; jc < nch; ++jc) {   // wave-uniform chunk loop
      const int j0 = jc * 64;

      f32x4 s[4] = {};
      #pragma unroll
      for (int nt = 0; nt < 4; ++nt) {
        const int krow = j0 + nt * 16 + r;
        bf16x8 kf0 = *(const bf16x8*)(Ksb + krow * 128 + lo0);
        s[nt] = MFMA16(qf[0], kf0, s[nt]);
        bf16x8 kf1 = *(const bf16x8*)(Ksb + krow * 128 + lo1);
        s[nt] = MFMA16(qf[1], kf1, s[nt]);
      }

      #pragma unroll
      for (int nt = 0; nt < 4; ++nt)
        #pragma unroll
        for (int rr = 0; rr < 4; ++rr) {
          const int i = i0 + qd * 4 + rr;
          const int j = j0 + nt * 16 + r;
          float p = __builtin_exp2f(fminf(s[nt][rr], 500.f) *
                                    0.1803368801111244f);  // *(1/8)*log2(e)
          if (j > i) p = 0.f;
          l_acc[ti][rr] += p;
          const int prow = qd * 4 + rr;
          const int pb = prow * 128 +
              (((nt * 2 + (r >> 3)) ^ (prow & 7)) << 4) + (r & 7) * 2;
          *(u16*)(Qw + pb) = f2b(p);
        }
      asm volatile("s_waitcnt lgkmcnt(0)" ::: "memory");

      bf16x8 pf[2];
      pf[0] = *(const bf16x8*)(Qw + r * 128 + lo0);
      pf[1] = *(const bf16x8*)(Qw + r * 128 + lo1);
      #pragma unroll
      for (int ntd = 0; ntd < 4; ++ntd) {
        const int vrow = ntd * 16 + r;
        bf16x8 vf0 = *(const bf16x8*)(Vtsb + vrow * 512 + j0 * 2 + lo0);
        o_acc[ti][ntd] = MFMA16(pf[0], vf0, o_acc[ti][ntd]);
        bf16x8 vf1 = *(const bf16x8*)(Vtsb + vrow * 512 + j0 * 2 + lo1);
        o_acc[ti][ntd] = MFMA16(pf[1], vf1, o_acc[ti][ntd]);
      }
    }
  }

  // ---- output: y layout [b][t][h][c][d] (faithful to the torch reshape) ----
  const size_t obase = ((size_t)b * 256) * 3072 + h * 384 + c * 64;
  #pragma unroll
  for (int ti = 0; ti < 2; ++ti) {
    const int i0 = tiles[ti] * 16;
    float linv[4];
    #pragma unroll
    for (int rr = 0; rr < 4; ++rr) {
      float sum = l_acc[ti][rr];
      sum += __shfl_xor(sum, 1, 16);
      sum += __shfl_xor(sum, 2, 16);
      sum += __shfl_xor(sum, 4, 16);
      sum += __shfl_xor(sum, 8, 16);
      linv[rr] = 1.f / sum;
    }
    #pragma unroll
    for (int ntd = 0; ntd < 4; ++ntd)
      #pragma unroll
      for (int rr = 0; rr < 4; ++rr) {
        const int t = i0 + qd * 4 + rr;
        const int d = ntd * 16 + r;
        y_ws[obase + (size_t)t * 3072 + d] = f2b(o_acc[ti][ntd][rr] * linv[rr]);
      }
  }
}

// ---------------------------------------------------------------------------
// BT-GEMM (round-0 verbatim, used for the output projection only).
// ---------------------------------------------------------------------------
__global__ __launch_bounds__(256, 3) void gemm_bt(
    const u16* __restrict__ A,
    const u16* W0, const u16* W1, const u16* W2,
    const float* bs0, const float* bs1, const float* bs2,
    u16* O0, u16* O1, u16* O2,
    float* OF,
    int qkv_mode)
{
  const int z = blockIdx.z;
  const u16* W    = (z == 0) ? W0 : (z == 1) ? W1 : W2;
  const float* bs = (z == 0) ? bs0 : (z == 1) ? bs1 : bs2;
  u16* O          = (z == 0) ? O0 : (z == 1) ? O1 : O2;

  const int m0 = blockIdx.x * 128;
  const int n0 = blockIdx.y * 128;

  __shared__ u16 As[128 * 32];   // 8 KB, 64B rows, chunk swizzle (q + (row>>1)) & 3
  __shared__ u16 Bs[128 * 32];

  const int tid  = threadIdx.x;
  const int lane = tid & 63;
  const int wv   = tid >> 6;
  const int r    = lane & 15;
  const int qd   = lane >> 4;
  const int wm   = (wv & 1) * 64;
  const int wn   = (wv >> 1) * 64;

  f32x4 acc[4][4] = {};

  for (int k0 = 0; k0 < 512; k0 += 32) {
    __syncthreads();
    #pragma unroll
    for (int it = 0; it < 2; ++it) {
      const int flat = (it * 256 + tid) * 16;       // byte offset in 8KB tile
      const int row  = flat >> 6;                   // 64 B per row
      const int swc  = (flat >> 4) & 3;
      const int gc   = (swc - (row >> 1)) & 3;      // un-swizzle for global side
      gl_lds16((const char*)A + (size_t)(m0 + row) * 1024 + k0 * 2 + gc * 16,
               (char*)As + flat);
      gl_lds16((const char*)W + (size_t)(n0 + row) * 1024 + k0 * 2 + gc * 16,
               (char*)Bs + flat);
    }
    __syncthreads();

    bf16x8 af[4], bf[4];
    #pragma unroll
    for (int mt = 0; mt < 4; ++mt) {
      const int row = wm + mt * 16 + r;
      const int sw  = (qd + (row >> 1)) & 3;
      af[mt] = *(const bf16x8*)((const char*)As + row * 64 + sw * 16);
    }
    #pragma unroll
    for (int nt = 0; nt < 4; ++nt) {
      const int row = wn + nt * 16 + r;
      const int sw  = (qd + (row >> 1)) & 3;
      bf[nt] = *(const bf16x8*)((const char*)Bs + row * 64 + sw * 16);
    }
    #pragma unroll
    for (int mt = 0; mt < 4; ++mt)
      #pragma unroll
      for (int nt = 0; nt < 4; ++nt)
        acc[mt][nt] = MFMA16(af[mt], bf[nt], acc[mt][nt]);
  }

  float bv[4];
  #pragma unroll
  for (int nt = 0; nt < 4; ++nt) bv[nt] = bs[n0 + wn + nt * 16 + r];

  if (qkv_mode) {
    #pragma unroll
    for (int mt = 0; mt < 4; ++mt) {
      #pragma unroll
      for (int rr = 0; rr < 4; ++rr) {
        const int m   = m0 + wm + mt * 16 + qd * 4 + rr;   // (b*T+t)*C + c
        const int b   = m / 1536;
        const int rem = m - b * 1536;
        const int t   = rem / 6;
        const int c   = rem - t * 6;
        #pragma unroll
        for (int nt = 0; nt < 4; ++nt) {
          const int f = n0 + wn + nt * 16 + r;             // h*64 + d
          const int hh = f >> 6;
          const int d = f & 63;
          const size_t addr = ((((size_t)b * 8 + hh) * 6 + c) * 256 + t) * 64 + d;
          O[addr] = f2b(acc[mt][nt][rr] + bv[nt]);
        }
      }
    }
  } else {
    #pragma unroll
    for (int mt = 0; mt < 4; ++mt) {
      #pragma unroll
      for (int rr = 0; rr < 4; ++rr) {
        const int m = m0 + wm + mt * 16 + qd * 4 + rr;
        #pragma unroll
        for (int nt = 0; nt < 4; ++nt) {
          const int f = n0 + wn + nt * 16 + r;
          OF[(size_t)m * 512 + f] = acc[mt][nt][rr] + bv[nt];   // fp32 output
        }
      }
    }
  }
}

// ---------------------------------------------------------------------------
extern "C" void kernel_launch(void* const* d_in, const int* in_sizes, int n_in,
                              void* d_out, int out_size, void* d_ws, size_t ws_size,
                              hipStream_t stream) {
  const float* x  = (const float*)d_in[0];
  const float* Wq = (const float*)d_in[1];
  const float* bq = (const float*)d_in[2];
  const float* Wk = (const float*)d_in[3];
  const float* bk = (const float*)d_in[4];
  const float* Wv = (const float*)d_in[5];
  const float* bv = (const float*)d_in[6];
  const float* Wp = (const float*)d_in[7];
  const float* bp = (const float*)d_in[8];
  float* out = (float*)d_out;                        // fp32 output

  const size_t PER_B = 256 * 6 * 512;       // 786432 elems per tensor per batch
  const size_t WSEG  = 4 * 262144;          // converted weights: Wq,Wk,Wv,Wp

  int NB = 16;
  while (NB > 1 && (WSEG + (size_t)2 * NB * PER_B) * 2 > ws_size) NB >>= 1;

  u16* wbf = (u16*)d_ws;                    // Wq | Wk | Wv | Wp (bf16)
  u16* Wpb = wbf + 3 * 262144;

  const size_t slab = (size_t)NB * PER_B;
  u16* xbf  = wbf + WSEG;
  u16* y_ws = xbf + slab;

  cvt_w<<<dim3(256, 4), 256, 0, stream>>>(Wq, Wk, Wv, Wp, wbf);

  const int nslab = 16 / NB;
  for (int s = 0; s < nslab; ++s) {
    const float* x_s  = x   + (size_t)s * NB * PER_B;
    float*      out_s = out + (size_t)s * NB * PER_B;
    cvt_x<<<dim3(NB * 768), 256, 0, stream>>>(x_s, xbf);
    qkv_attn<<<dim3(NB * 48), 512, 0, stream>>>(xbf, wbf, bq, bk, bv, y_ws);
    gemm_bt<<<dim3(NB * 12, 4, 1), 256, 0, stream>>>(
        y_ws, Wpb, Wpb, Wpb, bp, bp, bp, nullptr, nullptr, nullptr, out_s, 0);
  }
}